// Round 8
// baseline (169.606 us; speedup 1.0000x reference)
//
#include <hip/hip_runtime.h>
#include <stdint.h>

#define B_    32768
#define C_    64
#define D_    8
#define K15_  15
#define K16_  16
#define OUT_  512

typedef _Float16 half4v __attribute__((ext_vector_type(4)));
typedef _Float16 half8  __attribute__((ext_vector_type(8)));
typedef uint32_t uint4v __attribute__((ext_vector_type(4)));

// workspace layout (bytes)
#define AMAP_OFF  0
#define AMAP_SZ   32768                  // uint8 argmax per 15-bit code
#define S64_OFF   32768                  // fp64 S, k-major: S64[c][k][d]
#define S64_SZ    (64 * 15 * 8 * 8)      // 61440
#define T64_OFF   (S64_OFF + S64_SZ)     // 94208
#define T64_SZ    (64 * 15 * 8)          // 7680
#define IDX_OFF   (T64_OFF + T64_SZ)     // 101888
#define IDX_SZ    (B_ * C_)              // 2 MB. pairs mode: idxo unused ->
                                         // region reused for S32/T32.
#define S32_SZ    (64 * 15 * 8 * 4)      // 30720
#define PCT_OFF   (IDX_OFF + IDX_SZ)     // 2199040
#define PCT_SZ    (B_ * 32)              // 1 MB: pcT[p][rg][tr][i]
#define PTAB_OFF  (PCT_OFF + PCT_SZ)     // 3247616 (16B aligned)
#define PTAB_SZ   (32 * 32 * 256 * 16 * 2) // 8388608: P5[p][jc][q][16] fp16
#define WS_NEED   ((size_t)PTAB_OFF + PTAB_SZ)

// global_load_lds, width 16 B: LDS dest is wave-uniform base + lane*16
// (m104/m173) -> LDS layout must be linear in lane order.
__device__ __forceinline__ void gld_lds16(const void* g, void* l) {
    __builtin_amdgcn_global_load_lds(
        (const __attribute__((address_space(1))) void*)g,
        (__attribute__((address_space(3))) void*)l, 16, 0, 0);
}

// acc += (float)f16  via v_fma_mix_f32 (exact: cvt exact, *1.0 exact, fp32 add)
__device__ __forceinline__ void fma_mix_lo(float& acc, uint32_t w, float one) {
    asm("v_fma_mix_f32 %0, %1, %2, %0 op_sel_hi:[1,0,0]"
        : "+v"(acc) : "v"(w), "v"(one));
}
__device__ __forceinline__ void fma_mix_hi(float& acc, uint32_t w, float one) {
    asm("v_fma_mix_f32 %0, %1, %2, %0 op_sel:[1,0,0] op_sel_hi:[1,0,0]"
        : "+v"(acc) : "v"(w), "v"(one));
}

// ---------------------------------------------------------------------------
// k_setup (small): 129 blocks. Blocks 0..127 compute amap; block 128 builds
// S64/T64 (+ S32/T32 fp32 copies when flags&1). P5 build lives in k_codes6.
// ---------------------------------------------------------------------------
__global__ __launch_bounds__(256) void k_setup(const float* __restrict__ H,
                                               const float* __restrict__ S,
                                               const float* __restrict__ T,
                                               uint8_t* __restrict__ amap,
                                               double* __restrict__ S64,
                                               double* __restrict__ T64,
                                               float* __restrict__ S32,
                                               float* __restrict__ T32,
                                               int flags) {
    int gid = blockIdx.x * 256 + threadIdx.x;

    if (blockIdx.x < 128) {
        int code = gid;
        double h[K16_];
#pragma unroll
        for (int j = 0; j < K16_; ++j) h[j] = 0.0;
#pragma unroll
        for (int k = 0; k < K15_; ++k) {
            double s = ((code >> k) & 1) ? 1.0 : -1.0;
#pragma unroll
            for (int j = 0; j < K16_; ++j) h[j] += s * (double)H[k * K16_ + j];
        }
        double best = h[0];
        int bi = 0;
#pragma unroll
        for (int j = 1; j < K16_; ++j) {
            if (h[j] > best) { best = h[j]; bi = j; }
        }
        amap[code] = (uint8_t)bi;
    } else {
        for (int i = threadIdx.x; i < 64 * 15 * 8; i += 256) {
            int c = i / 120;
            int r = i - c * 120;  // r = k*8 + d
            int k = r >> 3;
            int d = r & 7;
            float sv = S[c * 120 + d * 15 + k];
            S64[i] = (double)sv;
            if (flags & 1) S32[i] = sv;
        }
        for (int i = threadIdx.x; i < 64 * 15; i += 256) {
            T64[i] = (double)T[i];
            if (flags & 1) T32[i] = T[i];
        }
    }
}

// ---------------------------------------------------------------------------
// k_codes6 (unchanged from R7 -- it delivered ~19 us): blocks [0,2048) =
// codes work; blocks [2048,4096) = P5 pair-table build (overlaps the
// latency-bound codes phase). fp32 dots + fp64 rescue (bit-identical codes).
// ---------------------------------------------------------------------------
#define XST3 579   // odd -> compute reads 2-way (free)
#define CPAD2 24   // uint16 row pad: 48 B rows -> 8B-aligned b64 end reads
template <int FAST>
__global__ __launch_bounds__(256, 6) void k_codes6(const float* __restrict__ x,
                                                   const double* __restrict__ S64,
                                                   const double* __restrict__ T64,
                                                   const float* __restrict__ S32,
                                                   const float* __restrict__ T32,
                                                   const uint8_t* __restrict__ amap,
                                                   uint8_t* __restrict__ idxo,
                                                   uint8_t* __restrict__ pcT,
                                                   const float* __restrict__ LUT,
                                                   _Float16* __restrict__ P5) {
    __shared__ float xls[8 * XST3];                     // 8 ch x 64 b x 9
    __shared__ alignas(16) uint16_t codesh[64 * CPAD2]; // [batch][local ch]

    if (FAST && blockIdx.x >= 2048) {
        // P5 build: gid bits [p:5][jc:5][q:8][e8:1] -> offset gid*8 halfs
        int gid = (blockIdx.x - 2048) * 256 + threadIdx.x;
        int e8 = gid & 1;
        int q = (gid >> 1) & 255;
        int jc = (gid >> 9) & 31;
        int p = gid >> 14;
        int t0 = q >> 4;
        int t1 = q & 15;
        int j0 = jc * 16 + e8 * 8;
        const float* u = LUT + (size_t)((2 * p) * 16 + t0) * 512 + j0;
        const float* v = LUT + (size_t)((2 * p + 1) * 16 + t1) * 512 + j0;
        float4 u0 = ((const float4*)u)[0];
        float4 u1 = ((const float4*)u)[1];
        float4 v0 = ((const float4*)v)[0];
        float4 v1 = ((const float4*)v)[1];
        half8 w;
        w[0] = (_Float16)(u0.x + v0.x);
        w[1] = (_Float16)(u0.y + v0.y);
        w[2] = (_Float16)(u0.z + v0.z);
        w[3] = (_Float16)(u0.w + v0.w);
        w[4] = (_Float16)(u1.x + v1.x);
        w[5] = (_Float16)(u1.y + v1.y);
        w[6] = (_Float16)(u1.z + v1.z);
        w[7] = (_Float16)(u1.w + v1.w);
        *(half8*)(P5 + (size_t)gid * 8) = w;
        return;
    }

    int bg = blockIdx.x >> 2;        // batch group: rows bg*64 .. +63
    int cq = blockIdx.x & 3;         // channel quarter: channels cq*16 .. +15
    int b0 = bg * 64;
    int lane = threadIdx.x & 63;
    int wv = __builtin_amdgcn_readfirstlane(threadIdx.x >> 6);
    int tid = threadIdx.x;

    // upfront loads: round r covers x columns cq*128 + r*64 + [0,64)
    float4 rgA[4], rgB[4];
#pragma unroll
    for (int t2 = 0; t2 < 4; ++t2) {
        int e = t2 * 256 + tid;
        int b = e >> 4;
        int j4 = e & 15;
        rgA[t2] = *(const float4*)(x + (size_t)(b0 + b) * 512 + cq * 128 +
                                   j4 * 4);
        rgB[t2] = *(const float4*)(x + (size_t)(b0 + b) * 512 + cq * 128 +
                                   64 + j4 * 4);
        asm volatile("" :: "v"(rgB[t2].x));  // pin: don't sink below compute
    }

#pragma unroll
    for (int r = 0; r < 2; ++r) {
#pragma unroll
        for (int t2 = 0; t2 < 4; ++t2) {   // write round r to LDS
            int e = t2 * 256 + tid;
            int b = e >> 4;
            int j4 = e & 15;
            int cl = j4 >> 1;
            int d0 = (j4 & 1) * 4;
            float4 v = (r == 0) ? rgA[t2] : rgB[t2];
            float* dst = &xls[cl * XST3 + b * 9 + d0];
            dst[0] = v.x; dst[1] = v.y; dst[2] = v.z; dst[3] = v.w;
        }
        __syncthreads();   // xls(round r) visible
#pragma unroll
        for (int i = 0; i < 2; ++i) {
            int cl = wv + i * 4;                 // wave-uniform, 0..7
            int c = cq * 16 + r * 8 + cl;        // global channel
            unsigned code = 0;
            if (FAST) {
                const float* Sc = S32 + c * 120;  // k-major: Sc[k*8+d]
                const float* Tc = T32 + c * 15;
                float xf[8];
#pragma unroll
                for (int d = 0; d < 8; ++d)
                    xf[d] = xls[cl * XST3 + lane * 9 + d];
                float pmin = 3.0e38f;
#pragma unroll
                for (int k = 0; k < K15_; ++k) {
                    float p = -Tc[k];
#pragma unroll
                    for (int d = 0; d < 8; ++d)
                        p = fmaf(xf[d], Sc[k * 8 + d], p);
                    code |= (p > 0.f) ? (1u << k) : 0u;
                    pmin = fminf(pmin, fabsf(p));
                }
                if (pmin < 1e-4f) {  // rare: redo channel in fp64
                    const double* Sd = S64 + c * 120;
                    const double* Td = T64 + c * 15;
                    code = 0;
#pragma unroll
                    for (int k = 0; k < K15_; ++k) {
                        double p = -Td[k];
#pragma unroll
                        for (int d = 0; d < 8; ++d)
                            p = fma((double)xf[d], Sd[k * 8 + d], p);
                        code |= (p > 0.0) ? (1u << k) : 0u;
                    }
                }
            } else {
                const double* Sc = S64 + c * 120;
                const double* Tc = T64 + c * 15;
                double xd[8];
#pragma unroll
                for (int d = 0; d < 8; ++d)
                    xd[d] = (double)xls[cl * XST3 + lane * 9 + d];
#pragma unroll
                for (int k = 0; k < K15_; ++k) {
                    double p = -Tc[k];
#pragma unroll
                    for (int d = 0; d < 8; ++d)
                        p = fma(xd[d], Sc[k * 8 + d], p);
                    code |= (p > 0.0) ? (1u << k) : 0u;
                }
            }
            codesh[lane * CPAD2 + r * 8 + cl] = (uint16_t)code;
        }
        __syncthreads();   // xls reads done (r=0: before overwrite) / codesh
    }

    // End phase: thread (bb,sub) owns batch bb, channels cq*16+sub*4..+3.
    int bb = tid >> 2;
    int sub = tid & 3;
    uint64_t cw8 = *(const uint64_t*)&codesh[bb * CPAD2 + sub * 4];  // one b64
    uint16_t cds[4];
    cds[0] = (uint16_t)(cw8 & 0xFFFF);
    cds[1] = (uint16_t)((cw8 >> 16) & 0xFFFF);
    cds[2] = (uint16_t)((cw8 >> 32) & 0xFFFF);
    cds[3] = (uint16_t)(cw8 >> 48);
    uint8_t ids[4];
#pragma unroll
    for (int j = 0; j < 4; ++j) ids[j] = amap[cds[j]];  // 4 indep gathers

    if (FAST) {
        int row = b0 + bb;
        int rg = row >> 10;
        int tr = row & 127;
        int i_ = (row & 1023) >> 7;
        uint8_t* base = pcT + rg * 1024 + tr * 8 + i_;
        int p0 = cq * 8 + sub * 2;
        base[(size_t)p0 * 32768] = (uint8_t)((ids[0] << 4) | ids[1]);
        base[(size_t)(p0 + 1) * 32768] = (uint8_t)((ids[2] << 4) | ids[3]);
    } else {
        uint32_t w0 = (uint32_t)ids[0] | ((uint32_t)ids[1] << 8) |
                      ((uint32_t)ids[2] << 16) | ((uint32_t)ids[3] << 24);
        *(uint32_t*)(idxo + (size_t)(b0 + bb) * 64 + cq * 16 + sub * 4) = w0;
    }
}

// ---------------------------------------------------------------------------
// k_main11: counted-vmcnt pipeline, v2 (k_main10's idea minus the spill).
// k_main10 failed because pinning 32 preloaded code-words made them co-live
// -> scratch spill (VGPR 40, WRITE_SIZE +9.3MB). v2 keeps k_main9's body and
// adds:
//   * 3 slab buffers (24 KB); stage(p+2) issued after barrier(p) into the
//     buffer gather(p-1) freed (all waves passed barrier(p) after gather(p-1)
//     in program order -> race-free).
//   * 3-deep rotating cw pipeline cw[3], statically indexed under full
//     unroll -> only 3 live registers, no spill.
//   * exact vmcnt counting: each iteration issues exactly 3 VMEM ops
//     {stage a, stage b, cw load}, fenced by sched_barrier(0) groups.
//     s_waitcnt vmcnt(3) at iter p retires {stage(p) a,b, cw(p)} (vmcnt
//     retires in issue order) and leaves {stage(p+1), cw(p+1)} in flight.
//     Raw s_barrier (no auto vmcnt(0) drain). Tail: p=31 drains vmcnt(0).
// Gather/accumulate identical to k_main9 (conflict fingerprint 7521216).
// ---------------------------------------------------------------------------
__global__ __launch_bounds__(256, 6) void k_main11(const uint8_t* __restrict__ pcT,
                                                   const _Float16* __restrict__ P5,
                                                   float* __restrict__ out) {
    __shared__ alignas(16) _Float16 slab[3][256 * 16];  // 3 x 8 KB, linear

    int rg5 = blockIdx.x >> 5;   // 0..63, owns rows rg5*512 + i*128 + tr
    int jc = blockIdx.x & 31;
    int t = threadIdx.x;
    int tc = t & 1;        // which 8-half piece of the 16-half chunk
    int tr = t >> 1;       // 0..127
    int lane = t & 63;
    int wv = __builtin_amdgcn_readfirstlane(t >> 6);  // wave-uniform

    // pcT[p][rg][tr][i_]: for row = rg5*512 + i*128 + tr:
    //   rg = rg5>>1, i_ = (rg5&1)*4 + i  -> 4 consecutive bytes
    const uint8_t* cbase = pcT + (rg5 >> 1) * 1024 + tr * 8 + (rg5 & 1) * 4;

    float acc[4][8];
#pragma unroll
    for (int i = 0; i < 4; ++i)
#pragma unroll
        for (int e = 0; e < 8; ++e) acc[i][e] = 0.f;
    float one = 1.0f;

    int hoff = wv * 512 + lane * 8;
    uint32_t cw[3];

    // prologue: two fenced issue groups, each exactly {stage a, b, cw load}
    {
        const _Float16* g0 = P5 + (size_t)jc * 4096 + hoff;
        gld_lds16(g0, &slab[0][wv * 512]);
        gld_lds16(g0 + 2048, &slab[0][wv * 512 + 2048]);
        cw[0] = *(const uint32_t*)cbase;
        __builtin_amdgcn_sched_barrier(0);
        const _Float16* g1 = P5 + (size_t)(32 + jc) * 4096 + hoff;
        gld_lds16(g1, &slab[1][wv * 512]);
        gld_lds16(g1 + 2048, &slab[1][wv * 512 + 2048]);
        cw[1] = *(const uint32_t*)(cbase + 32768);
        __builtin_amdgcn_sched_barrier(0);
    }

#pragma unroll
    for (int p = 0; p < 32; ++p) {
        // retire {stage(p) a,b, cw(p)}; leave {stage(p+1), cw(p+1)} in flight
        if (p < 31) asm volatile("s_waitcnt vmcnt(3)");
        else        asm volatile("s_waitcnt vmcnt(0)");
        __builtin_amdgcn_sched_barrier(0);
        __builtin_amdgcn_s_barrier();   // slab p complete; gather(p-1) done
        __builtin_amdgcn_sched_barrier(0);

        if (p < 30) {  // one fenced issue group: {stage(p+2) a,b, cw(p+2)}
            const _Float16* g =
                P5 + (size_t)((p + 2) * 32 + jc) * 4096 + hoff;
            _Float16* d = &slab[(p + 2) % 3][wv * 512];
            gld_lds16(g, d);
            gld_lds16(g + 2048, d + 2048);
            cw[(p + 2) % 3] = *(const uint32_t*)(cbase + (size_t)(p + 2) * 32768);
        }
        __builtin_amdgcn_sched_barrier(0);  // pin issues before gather

        const _Float16* rb = &slab[p % 3][0] + tc * 8;
        uint32_t cw_cur = cw[p % 3];
#pragma unroll
        for (int i = 0; i < 4; ++i) {
            int ci = (int)((cw_cur >> (8 * i)) & 0xFF);
            half8 v = *(const half8*)(rb + ci * 16);  // one ds_read_b128
            uint4v w = __builtin_bit_cast(uint4v, v);
#pragma unroll
            for (int e2 = 0; e2 < 4; ++e2) {
                fma_mix_lo(acc[i][2 * e2], w[e2], one);
                fma_mix_hi(acc[i][2 * e2 + 1], w[e2], one);
            }
        }
    }

#pragma unroll
    for (int i = 0; i < 4; ++i) {
        int row = rg5 * 512 + i * 128 + tr;
        float* o = out + (size_t)row * 512 + jc * 16 + tc * 8;
        float4 w0;
        w0.x = acc[i][0]; w0.y = acc[i][1]; w0.z = acc[i][2]; w0.w = acc[i][3];
        float4 w1;
        w1.x = acc[i][4]; w1.y = acc[i][5]; w1.z = acc[i][6]; w1.w = acc[i][7];
        ((float4*)o)[0] = w0;
        ((float4*)o)[1] = w1;
    }
}

// Fallback (small ws): direct 64-channel gather from fp32 LUT.
__global__ __launch_bounds__(256) void k_main_direct(const uint8_t* __restrict__ idx,
                                                     const float* __restrict__ LUT,
                                                     float* __restrict__ out) {
    int j4 = threadIdx.x & 127;
    int sub = threadIdx.x >> 7;
    int b0 = blockIdx.x * 16 + sub * 8;
    const float4* L4 = (const float4*)LUT;
    for (int r = 0; r < 8; ++r) {
        int b = b0 + r;
        const uint32_t* iw = (const uint32_t*)(idx + (size_t)b * 64);
        float4 acc;
        acc.x = 0.f; acc.y = 0.f; acc.z = 0.f; acc.w = 0.f;
#pragma unroll
        for (int i = 0; i < 16; ++i) {
            uint32_t w = __builtin_amdgcn_readfirstlane(iw[i]);
#pragma unroll
            for (int t = 0; t < 4; ++t) {
                int c = i * 4 + t;
                uint32_t codev = (w >> (8 * t)) & 0xFu;
                float4 v = L4[(size_t)(c * 16 + codev) * 128 + j4];
                acc.x += v.x; acc.y += v.y; acc.z += v.z; acc.w += v.w;
            }
        }
        ((float4*)(out + (size_t)b * 512))[j4] = acc;
    }
}

extern "C" void kernel_launch(void* const* d_in, const int* in_sizes, int n_in,
                              void* d_out, int out_size, void* d_ws, size_t ws_size,
                              hipStream_t stream) {
    const float* x   = (const float*)d_in[0];
    const float* S   = (const float*)d_in[1];
    const float* H   = (const float*)d_in[2];
    const float* T   = (const float*)d_in[3];
    const float* LUT = (const float*)d_in[4];
    float* out = (float*)d_out;

    uint8_t* ws = (uint8_t*)d_ws;
    uint8_t* amap = ws + AMAP_OFF;
    double* S64   = (double*)(ws + S64_OFF);
    double* T64   = (double*)(ws + T64_OFF);
    uint8_t* idxb = ws + IDX_OFF;                  // fallback mode only
    float* S32    = (float*)(ws + IDX_OFF);        // pairs mode only
    float* T32    = (float*)(ws + IDX_OFF + S32_SZ);
    uint8_t* pcTb = ws + PCT_OFF;
    _Float16* P5  = (_Float16*)(ws + PTAB_OFF);

    bool use_pairs = ws_size >= WS_NEED;

    hipLaunchKernelGGL(k_setup, dim3(129), dim3(256), 0, stream,
                       H, S, T, amap, S64, T64, S32, T32, use_pairs ? 1 : 0);
    if (use_pairs) {
        hipLaunchKernelGGL((k_codes6<1>), dim3(4096), dim3(256), 0, stream,
                           x, S64, T64, S32, T32, amap, idxb, pcTb, LUT, P5);
        hipLaunchKernelGGL(k_main11, dim3(2048), dim3(256), 0, stream,
                           pcTb, P5, out);
    } else {
        hipLaunchKernelGGL((k_codes6<0>), dim3(2048), dim3(256), 0, stream,
                           x, S64, T64, S32, T32, amap, idxb, pcTb, LUT, P5);
        hipLaunchKernelGGL(k_main_direct, dim3(B_ / 16), dim3(256), 0, stream,
                           idxb, LUT, out);
    }
}

// Round 9
// 163.712 us; speedup vs baseline: 1.0360x; 1.0360x over previous
//
#include <hip/hip_runtime.h>
#include <stdint.h>

#define B_    32768
#define C_    64
#define D_    8
#define K15_  15
#define K16_  16
#define OUT_  512

typedef _Float16 half4v __attribute__((ext_vector_type(4)));
typedef _Float16 half8  __attribute__((ext_vector_type(8)));
typedef uint32_t uint4v __attribute__((ext_vector_type(4)));

// workspace layout (bytes) -- reorganized: S64/T64 deleted (rescue casts
// fp32->fp64 inline, bit-identical), S32/T32 own a fixed slot so fallback
// (idxo) and pairs (pcT) modes never overlap them.
#define AMAP_OFF  0
#define AMAP_SZ   32768                   // uint8 argmax per 15-bit code
#define S32_OFF   32768                   // fp32 S, k-major: S32[c][k][d]
#define S32_SZ    (64 * 15 * 8 * 4)       // 30720
#define T32_OFF   (S32_OFF + S32_SZ)      // 63488
#define T32_SZ    (64 * 15 * 4)           // 3840
#define IDX_OFF   67584                   // fallback only: idx bytes (2 MB)
#define IDX_SZ    (B_ * C_)
#define PCT_OFF   (IDX_OFF + IDX_SZ)      // 2164736: pcT[p][rg][tr][i] (1 MB)
#define PCT_SZ    (B_ * 32)
#define PTAB_OFF  (PCT_OFF + PCT_SZ)      // 3213312 (16B aligned)
#define PTAB_SZ   (32 * 32 * 256 * 16 * 2) // 8388608: P5[p][jc][q][16] fp16
#define WS_NEED   ((size_t)PTAB_OFF + PTAB_SZ)   // 11601920

// global_load_lds, width 16 B: LDS dest is wave-uniform base + lane*16
// (m104/m173) -> LDS layout must be linear in lane order.
__device__ __forceinline__ void gld_lds16(const void* g, void* l) {
    __builtin_amdgcn_global_load_lds(
        (const __attribute__((address_space(1))) void*)g,
        (__attribute__((address_space(3))) void*)l, 16, 0, 0);
}

// acc += (float)f16  via v_fma_mix_f32 (exact: cvt exact, *1.0 exact, fp32 add)
__device__ __forceinline__ void fma_mix_lo(float& acc, uint32_t w, float one) {
    asm("v_fma_mix_f32 %0, %1, %2, %0 op_sel_hi:[1,0,0]"
        : "+v"(acc) : "v"(w), "v"(one));
}
__device__ __forceinline__ void fma_mix_hi(float& acc, uint32_t w, float one) {
    asm("v_fma_mix_f32 %0, %1, %2, %0 op_sel:[1,0,0] op_sel_hi:[1,0,0]"
        : "+v"(acc) : "v"(w), "v"(one));
}

// ---------------------------------------------------------------------------
// k_setup: 129 blocks. Blocks 0..127 compute amap (fp64 -- numerics
// untouched); block 128 builds S32 (k-major fp32 copy) + T32.
// ---------------------------------------------------------------------------
__global__ __launch_bounds__(256) void k_setup(const float* __restrict__ H,
                                               const float* __restrict__ S,
                                               const float* __restrict__ T,
                                               uint8_t* __restrict__ amap,
                                               float* __restrict__ S32,
                                               float* __restrict__ T32) {
    int gid = blockIdx.x * 256 + threadIdx.x;

    if (blockIdx.x < 128) {
        int code = gid;
        double h[K16_];
#pragma unroll
        for (int j = 0; j < K16_; ++j) h[j] = 0.0;
#pragma unroll
        for (int k = 0; k < K15_; ++k) {
            double s = ((code >> k) & 1) ? 1.0 : -1.0;
#pragma unroll
            for (int j = 0; j < K16_; ++j) h[j] += s * (double)H[k * K16_ + j];
        }
        double best = h[0];
        int bi = 0;
#pragma unroll
        for (int j = 1; j < K16_; ++j) {
            if (h[j] > best) { best = h[j]; bi = j; }
        }
        amap[code] = (uint8_t)bi;
    } else {
        for (int i = threadIdx.x; i < 64 * 15 * 8; i += 256) {
            int c = i / 120;
            int r = i - c * 120;  // r = k*8 + d
            int k = r >> 3;
            int d = r & 7;
            S32[i] = S[c * 120 + d * 15 + k];
        }
        for (int i = threadIdx.x; i < 64 * 15; i += 256) T32[i] = T[i];
    }
}

// ---------------------------------------------------------------------------
// k_codes7: register-direct codes -- ZERO LDS, ZERO barriers.
// The LDS transpose existed only to make S/T wave-uniform; assigning
// lane<->row, wave<->channel-group achieves that with direct per-lane x
// loads: thread = (row = bg*64+lane, channels c0..c0+3 with c0 = cq*16+wv*4)
// reads its own aligned 128 B of x (2 full cache lines, zero overfetch).
// S32/T32 remain wave-uniform scalar loads. fp32 dots + inline-cast fp64
// rescue when min|p| < 1e-4 -> codes bit-identical to the all-fp64 original.
// Blocks [2048,4096) (FAST only): P5 pair-table build (unchanged logic).
// ---------------------------------------------------------------------------
template <int FAST>
__global__ __launch_bounds__(256) void k_codes7(const float* __restrict__ x,
                                                const float* __restrict__ S32,
                                                const float* __restrict__ T32,
                                                const uint8_t* __restrict__ amap,
                                                uint8_t* __restrict__ idxo,
                                                uint8_t* __restrict__ pcT,
                                                const float* __restrict__ LUT,
                                                _Float16* __restrict__ P5) {
    if (FAST && blockIdx.x >= 2048) {
        // P5 build: gid bits [p:5][jc:5][q:8][e8:1] -> offset gid*8 halfs
        int gid = (blockIdx.x - 2048) * 256 + threadIdx.x;
        int e8 = gid & 1;
        int q = (gid >> 1) & 255;
        int jc = (gid >> 9) & 31;
        int p = gid >> 14;
        int t0 = q >> 4;
        int t1 = q & 15;
        int j0 = jc * 16 + e8 * 8;
        const float* u = LUT + (size_t)((2 * p) * 16 + t0) * 512 + j0;
        const float* v = LUT + (size_t)((2 * p + 1) * 16 + t1) * 512 + j0;
        float4 u0 = ((const float4*)u)[0];
        float4 u1 = ((const float4*)u)[1];
        float4 v0 = ((const float4*)v)[0];
        float4 v1 = ((const float4*)v)[1];
        half8 w;
        w[0] = (_Float16)(u0.x + v0.x);
        w[1] = (_Float16)(u0.y + v0.y);
        w[2] = (_Float16)(u0.z + v0.z);
        w[3] = (_Float16)(u0.w + v0.w);
        w[4] = (_Float16)(u1.x + v1.x);
        w[5] = (_Float16)(u1.y + v1.y);
        w[6] = (_Float16)(u1.z + v1.z);
        w[7] = (_Float16)(u1.w + v1.w);
        *(half8*)(P5 + (size_t)gid * 8) = w;
        return;
    }

    int bg = blockIdx.x >> 2;        // row group: rows bg*64 .. +63
    int cq = blockIdx.x & 3;         // channel quarter
    int lane = threadIdx.x & 63;
    int wv = __builtin_amdgcn_readfirstlane(threadIdx.x >> 6);
    int row = bg * 64 + lane;
    int c0 = cq * 16 + wv * 4;       // first of this thread's 4 channels

    // aligned 128-B per-lane read of x[row][c0*8 .. c0*8+32)
    const float4* xr = (const float4*)(x + (size_t)row * 512 + c0 * 8);
    float4 xv[8];
#pragma unroll
    for (int j = 0; j < 8; ++j) xv[j] = xr[j];

    uint8_t ids[4];
#pragma unroll
    for (int ch = 0; ch < 4; ++ch) {
        int c = c0 + ch;                      // wave-uniform
        const float* Sc = S32 + c * 120;      // k-major: Sc[k*8+d]
        const float* Tc = T32 + c * 15;
        float xf[8];
        xf[0] = xv[2 * ch].x; xf[1] = xv[2 * ch].y;
        xf[2] = xv[2 * ch].z; xf[3] = xv[2 * ch].w;
        xf[4] = xv[2 * ch + 1].x; xf[5] = xv[2 * ch + 1].y;
        xf[6] = xv[2 * ch + 1].z; xf[7] = xv[2 * ch + 1].w;
        unsigned code = 0;
        float pmin = 3.0e38f;
#pragma unroll
        for (int k = 0; k < K15_; ++k) {
            float p = -Tc[k];
#pragma unroll
            for (int d = 0; d < 8; ++d) p = fmaf(xf[d], Sc[k * 8 + d], p);
            code |= (p > 0.f) ? (1u << k) : 0u;
            pmin = fminf(pmin, fabsf(p));
        }
        if (pmin < 1e-4f) {  // rare: redo channel in fp64 (bit-identical to
                             // the original S64/T64 path: same values, order)
            code = 0;
#pragma unroll
            for (int k = 0; k < K15_; ++k) {
                double p = -(double)Tc[k];
#pragma unroll
                for (int d = 0; d < 8; ++d)
                    p = fma((double)xf[d], (double)Sc[k * 8 + d], p);
                code |= (p > 0.0) ? (1u << k) : 0u;
            }
        }
        ids[ch] = amap[code];
    }

    if (FAST) {
        // pcT[p][rg][tr][i_]; this thread's 4 channels = pairs p0, p0+1
        int rg = row >> 10;
        int tr = row & 127;
        int i_ = (row & 1023) >> 7;
        uint8_t* base = pcT + rg * 1024 + tr * 8 + i_;
        int p0 = c0 >> 1;
        base[(size_t)p0 * 32768] = (uint8_t)((ids[0] << 4) | ids[1]);
        base[(size_t)(p0 + 1) * 32768] = (uint8_t)((ids[2] << 4) | ids[3]);
    } else {
        uint32_t w = (uint32_t)ids[0] | ((uint32_t)ids[1] << 8) |
                     ((uint32_t)ids[2] << 16) | ((uint32_t)ids[3] << 24);
        *(uint32_t*)(idxo + (size_t)row * 64 + c0) = w;
    }
}

// ---------------------------------------------------------------------------
// k_main9 (restored verbatim from R6 -- proven 41.2 us; the counted-vmcnt
// variants R7/R8 were neutral-to-negative: TLP at 8 blocks/CU already hides
// the barrier drain). Slab staged via global_load_lds (width 16), linear
// [256][16] fp16 rows; double-buffered 2x8 KB -> 8 blocks/CU; prefetch
// issued right after the barrier. jc->XCD pinning via blk&31.
// Conflict fingerprint: 7521216.
// ---------------------------------------------------------------------------
__global__ __launch_bounds__(256, 8) void k_main9(const uint8_t* __restrict__ pcT,
                                                  const _Float16* __restrict__ P5,
                                                  float* __restrict__ out) {
    __shared__ alignas(16) _Float16 slab[2][256 * 16];  // 8 KB per buffer, linear

    int rg5 = blockIdx.x >> 5;   // 0..63, owns rows rg5*512 + i*128 + tr
    int jc = blockIdx.x & 31;
    int t = threadIdx.x;
    int tc = t & 1;        // which 8-half piece of the 16-half chunk
    int tr = t >> 1;       // 0..127
    int lane = t & 63;
    int wv = __builtin_amdgcn_readfirstlane(t >> 6);  // wave-uniform

    // pcT[p][rg][tr][i_]: for row = rg5*512 + i*128 + tr:
    //   rg = rg5>>1, i_ = (rg5&1)*4 + i  -> 4 consecutive bytes
    const uint8_t* cbase = pcT + (rg5 >> 1) * 1024 + tr * 8 + (rg5 & 1) * 4;

    float acc[4][8];
#pragma unroll
    for (int i = 0; i < 4; ++i)
#pragma unroll
        for (int e = 0; e < 8; ++e) acc[i][e] = 0.f;
    float one = 1.0f;

    // staging: wave wv covers halfs [wv*512 + lane*8) and [+2048) of the
    // 4096-half slab; global src mirrors the linear LDS dest exactly.
    int hoff = wv * 512 + lane * 8;

    // prologue: issue p=0 stage + load cw0
    {
        const _Float16* g = P5 + (size_t)jc * 4096 + hoff;
        gld_lds16(g, &slab[0][wv * 512]);
        gld_lds16(g + 2048, &slab[0][wv * 512 + 2048]);
    }
    uint32_t cw = *(const uint32_t*)cbase;
    uint32_t cwn = 0;

    for (int p = 0; p < 32; ++p) {
        // compiler emits s_waitcnt vmcnt(0) before s_barrier -> slab[p&1]
        // landed; barrier also fences gather(p-1) vs stage(p+1) (same buf).
        __syncthreads();

        if (p < 31) {
            const _Float16* g =
                P5 + (size_t)((p + 1) * 32 + jc) * 4096 + hoff;
            _Float16* d = &slab[(p + 1) & 1][wv * 512];
            gld_lds16(g, d);
            gld_lds16(g + 2048, d + 2048);
            cwn = *(const uint32_t*)(cbase + (size_t)(p + 1) * 32768);
        }

        const _Float16* rb = &slab[p & 1][0] + tc * 8;
        uint32_t cw_cur = cw;
#pragma unroll
        for (int i = 0; i < 4; ++i) {
            int ci = (int)((cw_cur >> (8 * i)) & 0xFF);
            half8 v = *(const half8*)(rb + ci * 16);  // one ds_read_b128
            uint4v w = __builtin_bit_cast(uint4v, v);
#pragma unroll
            for (int e2 = 0; e2 < 4; ++e2) {
                fma_mix_lo(acc[i][2 * e2], w[e2], one);
                fma_mix_hi(acc[i][2 * e2 + 1], w[e2], one);
            }
        }
        cw = cwn;
    }

#pragma unroll
    for (int i = 0; i < 4; ++i) {
        int row = rg5 * 512 + i * 128 + tr;
        float* o = out + (size_t)row * 512 + jc * 16 + tc * 8;
        float4 w0;
        w0.x = acc[i][0]; w0.y = acc[i][1]; w0.z = acc[i][2]; w0.w = acc[i][3];
        float4 w1;
        w1.x = acc[i][4]; w1.y = acc[i][5]; w1.z = acc[i][6]; w1.w = acc[i][7];
        ((float4*)o)[0] = w0;
        ((float4*)o)[1] = w1;
    }
}

// Fallback (small ws): direct 64-channel gather from fp32 LUT.
__global__ __launch_bounds__(256) void k_main_direct(const uint8_t* __restrict__ idx,
                                                     const float* __restrict__ LUT,
                                                     float* __restrict__ out) {
    int j4 = threadIdx.x & 127;
    int sub = threadIdx.x >> 7;
    int b0 = blockIdx.x * 16 + sub * 8;
    const float4* L4 = (const float4*)LUT;
    for (int r = 0; r < 8; ++r) {
        int b = b0 + r;
        const uint32_t* iw = (const uint32_t*)(idx + (size_t)b * 64);
        float4 acc;
        acc.x = 0.f; acc.y = 0.f; acc.z = 0.f; acc.w = 0.f;
#pragma unroll
        for (int i = 0; i < 16; ++i) {
            uint32_t w = __builtin_amdgcn_readfirstlane(iw[i]);
#pragma unroll
            for (int t = 0; t < 4; ++t) {
                int c = i * 4 + t;
                uint32_t codev = (w >> (8 * t)) & 0xFu;
                float4 v = L4[(size_t)(c * 16 + codev) * 128 + j4];
                acc.x += v.x; acc.y += v.y; acc.z += v.z; acc.w += v.w;
            }
        }
        ((float4*)(out + (size_t)b * 512))[j4] = acc;
    }
}

extern "C" void kernel_launch(void* const* d_in, const int* in_sizes, int n_in,
                              void* d_out, int out_size, void* d_ws, size_t ws_size,
                              hipStream_t stream) {
    const float* x   = (const float*)d_in[0];
    const float* S   = (const float*)d_in[1];
    const float* H   = (const float*)d_in[2];
    const float* T   = (const float*)d_in[3];
    const float* LUT = (const float*)d_in[4];
    float* out = (float*)d_out;

    uint8_t* ws = (uint8_t*)d_ws;
    uint8_t* amap = ws + AMAP_OFF;
    float* S32    = (float*)(ws + S32_OFF);
    float* T32    = (float*)(ws + T32_OFF);
    uint8_t* idxb = ws + IDX_OFF;                  // fallback mode only
    uint8_t* pcTb = ws + PCT_OFF;
    _Float16* P5  = (_Float16*)(ws + PTAB_OFF);

    bool use_pairs = ws_size >= WS_NEED;

    hipLaunchKernelGGL(k_setup, dim3(129), dim3(256), 0, stream,
                       H, S, T, amap, S32, T32);
    if (use_pairs) {
        hipLaunchKernelGGL((k_codes7<1>), dim3(4096), dim3(256), 0, stream,
                           x, S32, T32, amap, idxb, pcTb, LUT, P5);
        hipLaunchKernelGGL(k_main9, dim3(2048), dim3(256), 0, stream,
                           pcTb, P5, out);
    } else {
        hipLaunchKernelGGL((k_codes7<0>), dim3(2048), dim3(256), 0, stream,
                           x, S32, T32, amap, idxb, pcTb, LUT, P5);
        hipLaunchKernelGGL(k_main_direct, dim3(B_ / 16), dim3(256), 0, stream,
                           idxb, LUT, out);
    }
}